// Round 1
// baseline (214.166 us; speedup 1.0000x reference)
//
#include <hip/hip_runtime.h>
#include <hip/hip_bf16.h>

// Shapes fixed by the reference: N=16384 rows, C=1024, b=4096 groups of 4.
#define BGRP 4096
#define CDIM 1024

typedef __attribute__((ext_vector_type(8))) short bf16x8;
typedef __attribute__((ext_vector_type(4))) float f32x4;
typedef __attribute__((ext_vector_type(4))) unsigned short u16x4;

__device__ __forceinline__ float f2bf_bits_rne(float x) { return x; } // placeholder (unused)

__device__ __forceinline__ unsigned short f2bf(float x) {
    __hip_bfloat16 h = __float2bfloat16(x);
    unsigned short u;
    __builtin_memcpy(&u, &h, 2);
    return u;
}

// ---------------- block reduction helper (256 threads = 4 waves) -------------
template<int NV>
__device__ __forceinline__ void block_reduce(float* vals, float* lds) {
    const int lane = threadIdx.x & 63;
    const int wid  = threadIdx.x >> 6;
    #pragma unroll
    for (int v = 0; v < NV; ++v) {
        float x = vals[v];
        #pragma unroll
        for (int off = 32; off > 0; off >>= 1) x += __shfl_down(x, off, 64);
        if (lane == 0) lds[v * 4 + wid] = x;
    }
    __syncthreads();
    #pragma unroll
    for (int v = 0; v < NV; ++v)
        vals[v] = lds[v * 4 + 0] + lds[v * 4 + 1] + lds[v * 4 + 2] + lds[v * 4 + 3];
    __syncthreads();
}

// d: 10 packed upper-tri dots (raw rows, order (0,0),(0,1)..(3,3))
// coef[i] = softmax_i(sum_j G_ij) * inv_norm_i   where G = normalized Gram
__device__ __forceinline__ void group_coefs(const float* d, float* coef) {
    float D[4][4];
    int c = 0;
    #pragma unroll
    for (int i = 0; i < 4; ++i)
        #pragma unroll
        for (int j = i; j < 4; ++j) { D[i][j] = d[c]; D[j][i] = d[c]; ++c; }
    float inv[4];
    #pragma unroll
    for (int i = 0; i < 4; ++i) inv[i] = 1.0f / fmaxf(sqrtf(D[i][i]), 1e-12f);
    float s[4];
    #pragma unroll
    for (int i = 0; i < 4; ++i) {
        float si = 0.f;
        #pragma unroll
        for (int j = 0; j < 4; ++j) si += D[i][j] * inv[i] * inv[j];
        s[i] = si;
    }
    float m = fmaxf(fmaxf(s[0], s[1]), fmaxf(s[2], s[3]));
    float e[4], se = 0.f;
    #pragma unroll
    for (int i = 0; i < 4; ++i) { e[i] = expf(s[i] - m); se += e[i]; }
    float rse = 1.0f / se;
    #pragma unroll
    for (int i = 0; i < 4; ++i) coef[i] = e[i] * rse * inv[i];
}

// ---------------- Kernel A: group pooling for x1 & x2, one block per group ---
// Writes p1/p2 fp32 to d_out(+1), bf16 copies to ws, diag[g]=p1_g.p2_g,
// atomicAdd center distance.
__global__ __launch_bounds__(256) void pool_kernel(
    const float* __restrict__ x1, const float* __restrict__ x2,
    float* __restrict__ out,
    unsigned short* __restrict__ p1b, unsigned short* __restrict__ p2b,
    float* __restrict__ diag, float* __restrict__ center_acc)
{
    __shared__ float lds[80];
    const int g = blockIdx.x;
    const int t = threadIdx.x;

    float a1[4][4], a2[4][4];
    #pragma unroll
    for (int i = 0; i < 4; ++i) {
        float4 v1 = reinterpret_cast<const float4*>(x1)[(size_t)(4 * g + i) * 256 + t];
        float4 v2 = reinterpret_cast<const float4*>(x2)[(size_t)(4 * g + i) * 256 + t];
        a1[i][0] = v1.x; a1[i][1] = v1.y; a1[i][2] = v1.z; a1[i][3] = v1.w;
        a2[i][0] = v2.x; a2[i][1] = v2.y; a2[i][2] = v2.z; a2[i][3] = v2.w;
    }

    float red[20];
    {
        int c = 0;
        #pragma unroll
        for (int i = 0; i < 4; ++i)
            #pragma unroll
            for (int j = i; j < 4; ++j) {
                float s1 = 0.f, s2 = 0.f;
                #pragma unroll
                for (int e = 0; e < 4; ++e) {
                    s1 += a1[i][e] * a1[j][e];
                    s2 += a2[i][e] * a2[j][e];
                }
                red[c] = s1; red[10 + c] = s2;
                ++c;
            }
    }
    block_reduce<20>(red, lds);

    float c1[4], c2[4];
    group_coefs(red, c1);
    group_coefs(red + 10, c2);

    float q1[4], q2[4];
    #pragma unroll
    for (int e = 0; e < 4; ++e) {
        float s1 = 0.f, s2 = 0.f;
        #pragma unroll
        for (int i = 0; i < 4; ++i) { s1 += c1[i] * a1[i][e]; s2 += c2[i] * a2[i][e]; }
        q1[e] = s1; q2[e] = s2;
    }

    float red2[2];
    red2[0] = q1[0]*q1[0] + q1[1]*q1[1] + q1[2]*q1[2] + q1[3]*q1[3];
    red2[1] = q2[0]*q2[0] + q2[1]*q2[1] + q2[2]*q2[2] + q2[3]*q2[3];
    block_reduce<2>(red2, lds);
    const float i1 = 1.0f / fmaxf(sqrtf(red2[0]), 1e-12f);
    const float i2 = 1.0f / fmaxf(sqrtf(red2[1]), 1e-12f);

    float p1v[4], p2v[4];
    #pragma unroll
    for (int e = 0; e < 4; ++e) { p1v[e] = q1[e] * i1; p2v[e] = q2[e] * i2; }

    // fp32 outputs (d_out is offset by 1 for the scalar loss -> scalar stores)
    float* p1o = out + 1 + (size_t)g * CDIM + t * 4;
    float* p2o = p1o + (size_t)BGRP * CDIM;
    #pragma unroll
    for (int e = 0; e < 4; ++e) { p1o[e] = p1v[e]; p2o[e] = p2v[e]; }

    // bf16 copies for the MFMA stage
    if (p1b != nullptr) {
        u16x4 w1, w2;
        #pragma unroll
        for (int e = 0; e < 4; ++e) { w1[e] = f2bf(p1v[e]); w2[e] = f2bf(p2v[e]); }
        *reinterpret_cast<u16x4*>(p1b + (size_t)g * CDIM + t * 4) = w1;
        *reinterpret_cast<u16x4*>(p2b + (size_t)g * CDIM + t * 4) = w2;
    }

    // center distance (exact fp32) + exact diagonal sim_ii
    float red3[2];
    {
        float dsq = 0.f, dg = 0.f;
        #pragma unroll
        for (int e = 0; e < 4; ++e) {
            float d = p1v[e] - p2v[e];
            dsq += d * d;
            dg  += p1v[e] * p2v[e];
        }
        red3[0] = dsq; red3[1] = dg;
    }
    block_reduce<2>(red3, lds);
    if (t == 0) {
        atomicAdd(center_acc, sqrtf(red3[0]));
        diag[g] = red3[1];
    }
}

// ---------------- Kernel B: sim = p1 @ p2^T via bf16 MFMA, accumulate exp ----
__device__ __forceinline__ bf16x8 frag_from_f32(const float* p) {
    bf16x8 r;
    #pragma unroll
    for (int i = 0; i < 8; ++i) {
        unsigned int b = __float_as_uint(p[i]);
        b += 0x7fffu + ((b >> 16) & 1u);   // RNE to bf16
        r[i] = (short)(b >> 16);
    }
    return r;
}

template<bool FROM_WS>
__global__ __launch_bounds__(256) void sim_kernel(
    const unsigned short* __restrict__ p1b, const unsigned short* __restrict__ p2b,
    const float* __restrict__ p1f, const float* __restrict__ p2f,
    float* __restrict__ rowsum, float* __restrict__ colsum)
{
    const int lane = threadIdx.x & 63;
    const int wid  = threadIdx.x >> 6;
    const int wm = wid >> 1, wn = wid & 1;
    const int row0 = blockIdx.y * 128 + wm * 64;
    const int col0 = blockIdx.x * 128 + wn * 64;
    const int lr  = lane & 15;     // M/N index within 16x16 fragment
    const int lkb = lane >> 4;     // k-block 0..3
    const int lk  = lkb * 8;

    f32x4 acc[4][4];
    #pragma unroll
    for (int mi = 0; mi < 4; ++mi)
        #pragma unroll
        for (int ni = 0; ni < 4; ++ni) {
            acc[mi][ni][0] = 0.f; acc[mi][ni][1] = 0.f;
            acc[mi][ni][2] = 0.f; acc[mi][ni][3] = 0.f;
        }

    const size_t abase = (size_t)(row0 + lr) * CDIM + lk;
    const size_t bbase = (size_t)(col0 + lr) * CDIM + lk;

    for (int k = 0; k < CDIM; k += 32) {
        bf16x8 af[4], bfr[4];
        #pragma unroll
        for (int i = 0; i < 4; ++i) {
            if (FROM_WS) {
                af[i]  = *reinterpret_cast<const bf16x8*>(p1b + abase + (size_t)i * 16 * CDIM + k);
                bfr[i] = *reinterpret_cast<const bf16x8*>(p2b + bbase + (size_t)i * 16 * CDIM + k);
            } else {
                af[i]  = frag_from_f32(p1f + abase + (size_t)i * 16 * CDIM + k);
                bfr[i] = frag_from_f32(p2f + bbase + (size_t)i * 16 * CDIM + k);
            }
        }
        #pragma unroll
        for (int mi = 0; mi < 4; ++mi)
            #pragma unroll
            for (int ni = 0; ni < 4; ++ni)
                acc[mi][ni] = __builtin_amdgcn_mfma_f32_16x16x32_bf16(
                    af[mi], bfr[ni], acc[mi][ni], 0, 0, 0);
    }

    // exp() and row/col partial sums.
    // D layout: row = mi*16 + lkb*4 + r (r = reg), col = ni*16 + lr.
    float rs[4][4];
    float cs[4] = {0.f, 0.f, 0.f, 0.f};
    #pragma unroll
    for (int mi = 0; mi < 4; ++mi)
        #pragma unroll
        for (int r = 0; r < 4; ++r) rs[mi][r] = 0.f;

    #pragma unroll
    for (int mi = 0; mi < 4; ++mi)
        #pragma unroll
        for (int ni = 0; ni < 4; ++ni)
            #pragma unroll
            for (int r = 0; r < 4; ++r) {
                float e = expf(acc[mi][ni][r]);
                rs[mi][r] += e;
                cs[ni] += e;
            }

    #pragma unroll
    for (int mi = 0; mi < 4; ++mi)
        #pragma unroll
        for (int r = 0; r < 4; ++r) {
            float v = rs[mi][r];
            v += __shfl_xor(v, 1, 64);
            v += __shfl_xor(v, 2, 64);
            v += __shfl_xor(v, 4, 64);
            v += __shfl_xor(v, 8, 64);
            if (lr == 0) atomicAdd(&rowsum[row0 + mi * 16 + lkb * 4 + r], v);
        }
    #pragma unroll
    for (int ni = 0; ni < 4; ++ni) {
        float v = cs[ni];
        v += __shfl_xor(v, 16, 64);
        v += __shfl_xor(v, 32, 64);
        if (lkb == 0) atomicAdd(&colsum[col0 + ni * 16 + lr], v);
    }
}

// ---------------- Kernel C: final scalar loss ---------------------------------
__global__ __launch_bounds__(256) void loss_kernel(
    const float* __restrict__ rowsum, const float* __restrict__ colsum,
    const float* __restrict__ diag, const float* __restrict__ center,
    float* __restrict__ out)
{
    float part = 0.f;
    for (int i = threadIdx.x; i < BGRP; i += 256)
        part += logf(rowsum[i]) + logf(colsum[i]) - 2.0f * diag[i];
    #pragma unroll
    for (int off = 32; off > 0; off >>= 1) part += __shfl_down(part, off, 64);
    __shared__ float l4[4];
    if ((threadIdx.x & 63) == 0) l4[threadIdx.x >> 6] = part;
    __syncthreads();
    if (threadIdx.x == 0)
        out[0] = (l4[0] + l4[1] + l4[2] + l4[3] + center[0]) * (1.0f / (float)BGRP);
}

// ---------------- launch ------------------------------------------------------
extern "C" void kernel_launch(void* const* d_in, const int* in_sizes, int n_in,
                              void* d_out, int out_size, void* d_ws, size_t ws_size,
                              hipStream_t stream)
{
    const float* x1 = (const float*)d_in[0];
    const float* x2 = (const float*)d_in[1];
    float* out = (float*)d_out;

    float* rowsum = (float*)d_ws;               // 4096
    float* colsum = rowsum + BGRP;              // 4096
    float* diag   = colsum + BGRP;              // 4096
    float* center = diag + BGRP;                // 1 (padded to 16)
    const size_t head_floats = 3 * (size_t)BGRP + 16;   // 12304 -> byte off 49216 (16B aligned)
    unsigned short* p1b = (unsigned short*)((char*)d_ws + head_floats * sizeof(float));
    unsigned short* p2b = p1b + (size_t)BGRP * CDIM;
    const size_t need = head_floats * sizeof(float) + (size_t)2 * BGRP * CDIM * sizeof(unsigned short);
    const bool use_ws = (ws_size >= need);

    hipMemsetAsync(d_ws, 0, head_floats * sizeof(float), stream);

    pool_kernel<<<BGRP, 256, 0, stream>>>(x1, x2, out,
                                          use_ws ? p1b : nullptr,
                                          use_ws ? p2b : nullptr,
                                          diag, center);

    dim3 gridB(BGRP / 128, BGRP / 128);
    if (use_ws) {
        sim_kernel<true><<<gridB, 256, 0, stream>>>(p1b, p2b, nullptr, nullptr, rowsum, colsum);
    } else {
        sim_kernel<false><<<gridB, 256, 0, stream>>>(nullptr, nullptr,
                                                     out + 1, out + 1 + (size_t)BGRP * CDIM,
                                                     rowsum, colsum);
    }

    loss_kernel<<<1, 256, 0, stream>>>(rowsum, colsum, diag, center, out);
}

// Round 2
// 98.498 us; speedup vs baseline: 2.1743x; 2.1743x over previous
//
#include <hip/hip_runtime.h>
#include <hip/hip_bf16.h>

// Shapes fixed by the reference: N=16384 rows, C=1024, b=4096 groups of 4.
#define BGRP 4096
#define CDIM 1024

typedef __attribute__((ext_vector_type(8))) short bf16x8;
typedef __attribute__((ext_vector_type(4))) float f32x4;
typedef __attribute__((ext_vector_type(4))) unsigned short u16x4;

__device__ __forceinline__ unsigned short f2bf(float x) {
    __hip_bfloat16 h = __float2bfloat16(x);
    unsigned short u;
    __builtin_memcpy(&u, &h, 2);
    return u;
}

__device__ __forceinline__ void gload16(const void* g, void* l) {
    __builtin_amdgcn_global_load_lds(
        (const __attribute__((address_space(1))) unsigned int*)g,
        (__attribute__((address_space(3))) unsigned int*)l, 16, 0, 0);
}

// ---------------- block reduction helper (256 threads = 4 waves) -------------
template<int NV>
__device__ __forceinline__ void block_reduce(float* vals, float* lds) {
    const int lane = threadIdx.x & 63;
    const int wid  = threadIdx.x >> 6;
    #pragma unroll
    for (int v = 0; v < NV; ++v) {
        float x = vals[v];
        #pragma unroll
        for (int off = 32; off > 0; off >>= 1) x += __shfl_down(x, off, 64);
        if (lane == 0) lds[v * 4 + wid] = x;
    }
    __syncthreads();
    #pragma unroll
    for (int v = 0; v < NV; ++v)
        vals[v] = lds[v * 4 + 0] + lds[v * 4 + 1] + lds[v * 4 + 2] + lds[v * 4 + 3];
    __syncthreads();
}

// d: 10 packed upper-tri dots (raw rows, order (0,0),(0,1)..(3,3))
// coef[i] = softmax_i(sum_j G_ij) * inv_norm_i   where G = normalized Gram
__device__ __forceinline__ void group_coefs(const float* d, float* coef) {
    float D[4][4];
    int c = 0;
    #pragma unroll
    for (int i = 0; i < 4; ++i)
        #pragma unroll
        for (int j = i; j < 4; ++j) { D[i][j] = d[c]; D[j][i] = d[c]; ++c; }
    float inv[4];
    #pragma unroll
    for (int i = 0; i < 4; ++i) inv[i] = 1.0f / fmaxf(sqrtf(D[i][i]), 1e-12f);
    float s[4];
    #pragma unroll
    for (int i = 0; i < 4; ++i) {
        float si = 0.f;
        #pragma unroll
        for (int j = 0; j < 4; ++j) si += D[i][j] * inv[i] * inv[j];
        s[i] = si;
    }
    float m = fmaxf(fmaxf(s[0], s[1]), fmaxf(s[2], s[3]));
    float e[4], se = 0.f;
    #pragma unroll
    for (int i = 0; i < 4; ++i) { e[i] = expf(s[i] - m); se += e[i]; }
    float rse = 1.0f / se;
    #pragma unroll
    for (int i = 0; i < 4; ++i) coef[i] = e[i] * rse * inv[i];
}

// ---------------- Kernel A: group pooling for x1 & x2, one block per group ---
__global__ __launch_bounds__(256) void pool_kernel(
    const float* __restrict__ x1, const float* __restrict__ x2,
    float* __restrict__ out,
    unsigned short* __restrict__ p1b, unsigned short* __restrict__ p2b,
    float* __restrict__ diag, float* __restrict__ centerArr)
{
    __shared__ float lds[80];
    const int g = blockIdx.x;
    const int t = threadIdx.x;

    float a1[4][4], a2[4][4];
    #pragma unroll
    for (int i = 0; i < 4; ++i) {
        float4 v1 = reinterpret_cast<const float4*>(x1)[(size_t)(4 * g + i) * 256 + t];
        float4 v2 = reinterpret_cast<const float4*>(x2)[(size_t)(4 * g + i) * 256 + t];
        a1[i][0] = v1.x; a1[i][1] = v1.y; a1[i][2] = v1.z; a1[i][3] = v1.w;
        a2[i][0] = v2.x; a2[i][1] = v2.y; a2[i][2] = v2.z; a2[i][3] = v2.w;
    }

    float red[20];
    {
        int c = 0;
        #pragma unroll
        for (int i = 0; i < 4; ++i)
            #pragma unroll
            for (int j = i; j < 4; ++j) {
                float s1 = 0.f, s2 = 0.f;
                #pragma unroll
                for (int e = 0; e < 4; ++e) {
                    s1 += a1[i][e] * a1[j][e];
                    s2 += a2[i][e] * a2[j][e];
                }
                red[c] = s1; red[10 + c] = s2;
                ++c;
            }
    }
    block_reduce<20>(red, lds);

    float c1[4], c2[4];
    group_coefs(red, c1);
    group_coefs(red + 10, c2);

    float q1[4], q2[4];
    #pragma unroll
    for (int e = 0; e < 4; ++e) {
        float s1 = 0.f, s2 = 0.f;
        #pragma unroll
        for (int i = 0; i < 4; ++i) { s1 += c1[i] * a1[i][e]; s2 += c2[i] * a2[i][e]; }
        q1[e] = s1; q2[e] = s2;
    }

    // One reduce for {|q1|^2, |q2|^2, q1.q2}; center & diag are closed-form.
    float red2[3];
    red2[0] = q1[0]*q1[0] + q1[1]*q1[1] + q1[2]*q1[2] + q1[3]*q1[3];
    red2[1] = q2[0]*q2[0] + q2[1]*q2[1] + q2[2]*q2[2] + q2[3]*q2[3];
    red2[2] = q1[0]*q2[0] + q1[1]*q2[1] + q1[2]*q2[2] + q1[3]*q2[3];
    block_reduce<3>(red2, lds);
    const float n1 = red2[0], n2 = red2[1], d12 = red2[2];
    const float i1 = 1.0f / fmaxf(sqrtf(n1), 1e-12f);
    const float i2 = 1.0f / fmaxf(sqrtf(n2), 1e-12f);

    float p1v[4], p2v[4];
    #pragma unroll
    for (int e = 0; e < 4; ++e) { p1v[e] = q1[e] * i1; p2v[e] = q2[e] * i2; }

    // fp32 outputs (d_out is offset by 1 for the scalar loss)
    float* p1o = out + 1 + (size_t)g * CDIM + t * 4;
    float* p2o = p1o + (size_t)BGRP * CDIM;
    #pragma unroll
    for (int e = 0; e < 4; ++e) { p1o[e] = p1v[e]; p2o[e] = p2v[e]; }

    // bf16 copies for the MFMA stage
    if (p1b != nullptr) {
        u16x4 w1, w2;
        #pragma unroll
        for (int e = 0; e < 4; ++e) { w1[e] = f2bf(p1v[e]); w2[e] = f2bf(p2v[e]); }
        *reinterpret_cast<u16x4*>(p1b + (size_t)g * CDIM + t * 4) = w1;
        *reinterpret_cast<u16x4*>(p2b + (size_t)g * CDIM + t * 4) = w2;
    }

    if (t == 0) {
        const float dg = i1 * i2 * d12;          // p1 . p2  (exact fp32)
        diag[g] = dg;
        const float c2v = fmaxf(n1 * i1 * i1 + n2 * i2 * i2 - 2.0f * dg, 0.0f);
        centerArr[g] = sqrtf(c2v);               // ||p1 - p2||
    }
}

// ---------------- Kernel B: sim = p1 @ p2^T, m97-style LDS-staged MFMA -------
// 128x128 block tile, BK=64, 4 waves in 2x2, 64x64 per wave.
// LDS linear [128][64] bf16 per operand; T2 swizzle applied by pre-swizzling
// the per-lane global source (global_load_lds writes linearly) and XOR-ing
// the ds_read column:  physcol = col ^ ((row&7)<<4)   (byte units, 16B quanta).
__global__ __launch_bounds__(256, 4) void sim_lds_kernel(
    const unsigned short* __restrict__ p1b, const unsigned short* __restrict__ p2b,
    float* __restrict__ rowsum, float* __restrict__ colsum)
{
    __shared__ __align__(16) unsigned char lds[32768];   // A: [0,16K)  B: [16K,32K)
    const int tid  = threadIdx.x;
    const int lane = tid & 63;
    const int wid  = tid >> 6;
    const int wm = wid >> 1, wn = wid & 1;
    const int row0 = blockIdx.y * 128;
    const int col0 = blockIdx.x * 128;
    const int lr  = lane & 15;     // M/N index within 16x16 fragment
    const int lkb = lane >> 4;     // k-subgroup 0..3

    // staging geometry: each 1KB chunk = 8 rows x 128B; lane covers
    // physical (row = chunk*8 + lane/8, colbyte = (lane&7)*16).
    // Inverse-swizzled source col: 16*((lane&7) ^ (lane/8)).
    const int srow = lane >> 3;
    const int scol = ((lane & 7) ^ srow) << 4;
    const int ch0  = wid * 4;      // 4 chunks per wave per operand

    f32x4 acc[4][4];
    #pragma unroll
    for (int mi = 0; mi < 4; ++mi)
        #pragma unroll
        for (int ni = 0; ni < 4; ++ni) {
            acc[mi][ni][0] = 0.f; acc[mi][ni][1] = 0.f;
            acc[mi][ni][2] = 0.f; acc[mi][ni][3] = 0.f;
        }

    const char* A = (const char*)p1b;   // row stride 2048 B
    const char* B = (const char*)p2b;

    for (int kt = 0; kt < 16; ++kt) {
        const size_t kbyte = (size_t)kt * 128;
        #pragma unroll
        for (int c = 0; c < 4; ++c) {
            const int chunk = ch0 + c;
            const int r = chunk * 8 + srow;
            gload16(A + (size_t)(row0 + r) * 2048 + kbyte + scol, lds + chunk * 1024);
            gload16(B + (size_t)(col0 + r) * 2048 + kbyte + scol, lds + 16384 + chunk * 1024);
        }
        __syncthreads();   // drains vmcnt -> staged data visible

        #pragma unroll
        for (int ks = 0; ks < 2; ++ks) {
            bf16x8 af[4], bg[4];
            const int cbase = (ks * 64 + lkb * 16) ^ ((lr & 7) << 4);
            #pragma unroll
            for (int i = 0; i < 4; ++i) {
                const int ra = wm * 64 + i * 16 + lr;
                const int rb = wn * 64 + i * 16 + lr;
                af[i] = *reinterpret_cast<const bf16x8*>(lds + ra * 128 + cbase);
                bg[i] = *reinterpret_cast<const bf16x8*>(lds + 16384 + rb * 128 + cbase);
            }
            #pragma unroll
            for (int mi = 0; mi < 4; ++mi)
                #pragma unroll
                for (int ni = 0; ni < 4; ++ni)
                    acc[mi][ni] = __builtin_amdgcn_mfma_f32_16x16x32_bf16(
                        af[mi], bg[ni], acc[mi][ni], 0, 0, 0);
        }
        __syncthreads();   // reads done before next stage overwrites
    }

    // exp() and row/col partial sums.
    // D layout: row = mi*16 + lkb*4 + r (r = reg), col = ni*16 + lr.
    float rs[4][4];
    float cs[4] = {0.f, 0.f, 0.f, 0.f};
    #pragma unroll
    for (int mi = 0; mi < 4; ++mi)
        #pragma unroll
        for (int r = 0; r < 4; ++r) rs[mi][r] = 0.f;

    #pragma unroll
    for (int mi = 0; mi < 4; ++mi)
        #pragma unroll
        for (int ni = 0; ni < 4; ++ni)
            #pragma unroll
            for (int r = 0; r < 4; ++r) {
                float e = __expf(acc[mi][ni][r]);
                rs[mi][r] += e;
                cs[ni] += e;
            }

    const int wrow0 = row0 + wm * 64;
    const int wcol0 = col0 + wn * 64;
    #pragma unroll
    for (int mi = 0; mi < 4; ++mi)
        #pragma unroll
        for (int r = 0; r < 4; ++r) {
            float v = rs[mi][r];
            v += __shfl_xor(v, 1, 64);
            v += __shfl_xor(v, 2, 64);
            v += __shfl_xor(v, 4, 64);
            v += __shfl_xor(v, 8, 64);
            if (lr == 0) atomicAdd(&rowsum[wrow0 + mi * 16 + lkb * 4 + r], v);
        }
    #pragma unroll
    for (int ni = 0; ni < 4; ++ni) {
        float v = cs[ni];
        v += __shfl_xor(v, 16, 64);
        v += __shfl_xor(v, 32, 64);
        if (lkb == 0) atomicAdd(&colsum[wcol0 + ni * 16 + lr], v);
    }
}

// ---------------- fallback sim (no ws): read fp32 p1/p2 from out -------------
__device__ __forceinline__ bf16x8 frag_from_f32(const float* p) {
    bf16x8 r;
    #pragma unroll
    for (int i = 0; i < 8; ++i) {
        unsigned int b = __float_as_uint(p[i]);
        b += 0x7fffu + ((b >> 16) & 1u);   // RNE to bf16
        r[i] = (short)(b >> 16);
    }
    return r;
}

__global__ __launch_bounds__(256) void sim_fallback_kernel(
    const float* __restrict__ p1f, const float* __restrict__ p2f,
    float* __restrict__ rowsum, float* __restrict__ colsum)
{
    const int lane = threadIdx.x & 63;
    const int wid  = threadIdx.x >> 6;
    const int wm = wid >> 1, wn = wid & 1;
    const int row0 = blockIdx.y * 128 + wm * 64;
    const int col0 = blockIdx.x * 128 + wn * 64;
    const int lr  = lane & 15;
    const int lkb = lane >> 4;
    const int lk  = lkb * 8;

    f32x4 acc[4][4];
    #pragma unroll
    for (int mi = 0; mi < 4; ++mi)
        #pragma unroll
        for (int ni = 0; ni < 4; ++ni) {
            acc[mi][ni][0] = 0.f; acc[mi][ni][1] = 0.f;
            acc[mi][ni][2] = 0.f; acc[mi][ni][3] = 0.f;
        }

    const size_t abase = (size_t)(row0 + lr) * CDIM + lk;
    const size_t bbase = (size_t)(col0 + lr) * CDIM + lk;

    for (int k = 0; k < CDIM; k += 32) {
        bf16x8 af[4], bfr[4];
        #pragma unroll
        for (int i = 0; i < 4; ++i) {
            af[i]  = frag_from_f32(p1f + abase + (size_t)i * 16 * CDIM + k);
            bfr[i] = frag_from_f32(p2f + bbase + (size_t)i * 16 * CDIM + k);
        }
        #pragma unroll
        for (int mi = 0; mi < 4; ++mi)
            #pragma unroll
            for (int ni = 0; ni < 4; ++ni)
                acc[mi][ni] = __builtin_amdgcn_mfma_f32_16x16x32_bf16(
                    af[mi], bfr[ni], acc[mi][ni], 0, 0, 0);
    }

    float rs[4][4];
    float cs[4] = {0.f, 0.f, 0.f, 0.f};
    #pragma unroll
    for (int mi = 0; mi < 4; ++mi)
        #pragma unroll
        for (int r = 0; r < 4; ++r) rs[mi][r] = 0.f;

    #pragma unroll
    for (int mi = 0; mi < 4; ++mi)
        #pragma unroll
        for (int ni = 0; ni < 4; ++ni)
            #pragma unroll
            for (int r = 0; r < 4; ++r) {
                float e = __expf(acc[mi][ni][r]);
                rs[mi][r] += e;
                cs[ni] += e;
            }

    #pragma unroll
    for (int mi = 0; mi < 4; ++mi)
        #pragma unroll
        for (int r = 0; r < 4; ++r) {
            float v = rs[mi][r];
            v += __shfl_xor(v, 1, 64);
            v += __shfl_xor(v, 2, 64);
            v += __shfl_xor(v, 4, 64);
            v += __shfl_xor(v, 8, 64);
            if (lr == 0) atomicAdd(&rowsum[row0 + mi * 16 + lkb * 4 + r], v);
        }
    #pragma unroll
    for (int ni = 0; ni < 4; ++ni) {
        float v = cs[ni];
        v += __shfl_xor(v, 16, 64);
        v += __shfl_xor(v, 32, 64);
        if (lkb == 0) atomicAdd(&colsum[col0 + ni * 16 + lr], v);
    }
}

// ---------------- Kernel C: final scalar loss ---------------------------------
__global__ __launch_bounds__(256) void loss_kernel(
    const float* __restrict__ rowsum, const float* __restrict__ colsum,
    const float* __restrict__ diag, const float* __restrict__ centerArr,
    float* __restrict__ out)
{
    float part = 0.f;
    for (int i = threadIdx.x; i < BGRP; i += 256)
        part += logf(rowsum[i]) + logf(colsum[i]) - 2.0f * diag[i] + centerArr[i];
    #pragma unroll
    for (int off = 32; off > 0; off >>= 1) part += __shfl_down(part, off, 64);
    __shared__ float l4[4];
    if ((threadIdx.x & 63) == 0) l4[threadIdx.x >> 6] = part;
    __syncthreads();
    if (threadIdx.x == 0)
        out[0] = (l4[0] + l4[1] + l4[2] + l4[3]) * (1.0f / (float)BGRP);
}

// ---------------- launch ------------------------------------------------------
extern "C" void kernel_launch(void* const* d_in, const int* in_sizes, int n_in,
                              void* d_out, int out_size, void* d_ws, size_t ws_size,
                              hipStream_t stream)
{
    const float* x1 = (const float*)d_in[0];
    const float* x2 = (const float*)d_in[1];
    float* out = (float*)d_out;

    float* rowsum    = (float*)d_ws;            // 4096
    float* colsum    = rowsum + BGRP;           // 4096
    float* diag      = colsum + BGRP;           // 4096
    float* centerArr = diag + BGRP;             // 4096
    const size_t head_floats = 4 * (size_t)BGRP;       // 64 KB, 16B aligned
    unsigned short* p1b = (unsigned short*)((char*)d_ws + head_floats * sizeof(float));
    unsigned short* p2b = p1b + (size_t)BGRP * CDIM;
    const size_t need = head_floats * sizeof(float) + (size_t)2 * BGRP * CDIM * sizeof(unsigned short);
    const bool use_ws = (ws_size >= need);

    // only rowsum/colsum need zeroing (diag/centerArr fully overwritten)
    hipMemsetAsync(d_ws, 0, 2 * (size_t)BGRP * sizeof(float), stream);

    pool_kernel<<<BGRP, 256, 0, stream>>>(x1, x2, out,
                                          use_ws ? p1b : nullptr,
                                          use_ws ? p2b : nullptr,
                                          diag, centerArr);

    dim3 gridB(BGRP / 128, BGRP / 128);
    if (use_ws) {
        sim_lds_kernel<<<gridB, 256, 0, stream>>>(p1b, p2b, rowsum, colsum);
    } else {
        sim_fallback_kernel<<<gridB, 256, 0, stream>>>(out + 1, out + 1 + (size_t)BGRP * CDIM,
                                                       rowsum, colsum);
    }

    loss_kernel<<<1, 256, 0, stream>>>(rowsum, colsum, diag, centerArr, out);
}

// Round 3
// 87.267 us; speedup vs baseline: 2.4542x; 1.1287x over previous
//
#include <hip/hip_runtime.h>
#include <hip/hip_bf16.h>

// Shapes fixed by the reference: N=16384 rows, C=1024, b=4096 groups of 4.
#define BGRP 4096
#define CDIM 1024

typedef __attribute__((ext_vector_type(8))) short bf16x8;
typedef __attribute__((ext_vector_type(4))) float f32x4;
typedef __attribute__((ext_vector_type(4))) unsigned short u16x4;

__device__ __forceinline__ unsigned short f2bf(float x) {
    __hip_bfloat16 h = __float2bfloat16(x);
    unsigned short u;
    __builtin_memcpy(&u, &h, 2);
    return u;
}

__device__ __forceinline__ void gload16(const void* g, void* l) {
    __builtin_amdgcn_global_load_lds(
        (const __attribute__((address_space(1))) unsigned int*)g,
        (__attribute__((address_space(3))) unsigned int*)l, 16, 0, 0);
}

// d: 10 packed upper-tri dots (raw rows, order (0,0),(0,1)..(3,3))
// coef[i] = softmax_i(sum_j G_ij) * inv_norm_i   where G = normalized Gram
__device__ __forceinline__ void group_coefs(const float* d, float* coef) {
    float D[4][4];
    int c = 0;
    #pragma unroll
    for (int i = 0; i < 4; ++i)
        #pragma unroll
        for (int j = i; j < 4; ++j) { D[i][j] = d[c]; D[j][i] = d[c]; ++c; }
    float inv[4];
    #pragma unroll
    for (int i = 0; i < 4; ++i) inv[i] = 1.0f / fmaxf(sqrtf(D[i][i]), 1e-12f);
    float s[4];
    #pragma unroll
    for (int i = 0; i < 4; ++i) {
        float si = 0.f;
        #pragma unroll
        for (int j = 0; j < 4; ++j) si += D[i][j] * inv[i] * inv[j];
        s[i] = si;
    }
    float m = fmaxf(fmaxf(s[0], s[1]), fmaxf(s[2], s[3]));
    float e[4], se = 0.f;
    #pragma unroll
    for (int i = 0; i < 4; ++i) { e[i] = expf(s[i] - m); se += e[i]; }
    float rse = 1.0f / se;
    #pragma unroll
    for (int i = 0; i < 4; ++i) coef[i] = e[i] * rse * inv[i];
}

__device__ __forceinline__ float wave_allsum(float t) {
    t += __shfl_xor(t, 1, 64);
    t += __shfl_xor(t, 2, 64);
    t += __shfl_xor(t, 4, 64);
    t += __shfl_xor(t, 8, 64);
    t += __shfl_xor(t, 16, 64);
    t += __shfl_xor(t, 32, 64);
    return t;
}

// ---------------- Kernel A: group pooling, ONE WAVE per group ----------------
// Wave-synchronous: no barriers, no LDS. Lane l owns elements w*256 + l*4.
// |q|^2 closed-form from Gram (c^T D c) -> only one extra 1-value reduction
// (p1.p2) beyond the Gram reduction.
__device__ __forceinline__ void pool_phase(
    const float* __restrict__ x, int g, int l,
    float* __restrict__ pout,            // fp32 out (base misaligned by 1 float -> scalar stores)
    unsigned short* __restrict__ pbout,  // bf16 out (8B aligned) or null
    float4 p[4], float& s_out)
{
    float4 a[4][4];
    #pragma unroll
    for (int i = 0; i < 4; ++i)
        #pragma unroll
        for (int w = 0; w < 4; ++w)
            a[i][w] = reinterpret_cast<const float4*>(x)[(size_t)(4 * g + i) * 256 + w * 64 + l];

    float dd[10];
    {
        int c = 0;
        #pragma unroll
        for (int i = 0; i < 4; ++i)
            #pragma unroll
            for (int j = i; j < 4; ++j) {
                float s0 = 0.f;
                #pragma unroll
                for (int w = 0; w < 4; ++w)
                    s0 += a[i][w].x * a[j][w].x + a[i][w].y * a[j][w].y
                        + a[i][w].z * a[j][w].z + a[i][w].w * a[j][w].w;
                dd[c++] = s0;
            }
    }
    #pragma unroll
    for (int v = 0; v < 10; ++v) dd[v] = wave_allsum(dd[v]);

    float coef[4];
    group_coefs(dd, coef);

    // n = |q|^2 = sum_ij coef_i coef_j D_ij  (closed form, no reduction)
    float D[4][4];
    {
        int c = 0;
        #pragma unroll
        for (int i = 0; i < 4; ++i)
            #pragma unroll
            for (int j = i; j < 4; ++j) { D[i][j] = dd[c]; D[j][i] = dd[c]; ++c; }
    }
    float n = 0.f;
    #pragma unroll
    for (int i = 0; i < 4; ++i) {
        float ti = 0.f;
        #pragma unroll
        for (int j = 0; j < 4; ++j) ti += D[i][j] * coef[j];
        n += coef[i] * ti;
    }
    const float inv = 1.0f / fmaxf(sqrtf(n), 1e-12f);
    s_out = n * inv * inv;

    #pragma unroll
    for (int w = 0; w < 4; ++w) {
        float4 q;
        q.x = coef[0]*a[0][w].x + coef[1]*a[1][w].x + coef[2]*a[2][w].x + coef[3]*a[3][w].x;
        q.y = coef[0]*a[0][w].y + coef[1]*a[1][w].y + coef[2]*a[2][w].y + coef[3]*a[3][w].y;
        q.z = coef[0]*a[0][w].z + coef[1]*a[1][w].z + coef[2]*a[2][w].z + coef[3]*a[3][w].z;
        q.w = coef[0]*a[0][w].w + coef[1]*a[1][w].w + coef[2]*a[2][w].w + coef[3]*a[3][w].w;
        q.x *= inv; q.y *= inv; q.z *= inv; q.w *= inv;
        p[w] = q;

        const int e = w * 256 + l * 4;
        pout[e + 0] = q.x; pout[e + 1] = q.y; pout[e + 2] = q.z; pout[e + 3] = q.w;
        if (pbout != nullptr) {
            u16x4 wb;
            wb[0] = f2bf(q.x); wb[1] = f2bf(q.y); wb[2] = f2bf(q.z); wb[3] = f2bf(q.w);
            *reinterpret_cast<u16x4*>(pbout + e) = wb;
        }
    }
}

__global__ __launch_bounds__(256, 3) void pool_kernel(
    const float* __restrict__ x1, const float* __restrict__ x2,
    float* __restrict__ out,
    unsigned short* __restrict__ p1b, unsigned short* __restrict__ p2b,
    float* __restrict__ diag, float* __restrict__ centerArr)
{
    const int l = threadIdx.x & 63;
    const int g = blockIdx.x * 4 + (threadIdx.x >> 6);

    float4 p1s[4], p2s[4];
    float s1, s2;
    pool_phase(x1, g, l, out + 1 + (size_t)g * CDIM,
               p1b ? p1b + (size_t)g * CDIM : nullptr, p1s, s1);
    pool_phase(x2, g, l, out + 1 + (size_t)(BGRP + g) * CDIM,
               p2b ? p2b + (size_t)g * CDIM : nullptr, p2s, s2);

    float dp = 0.f;
    #pragma unroll
    for (int w = 0; w < 4; ++w)
        dp += p1s[w].x * p2s[w].x + p1s[w].y * p2s[w].y
            + p1s[w].z * p2s[w].z + p1s[w].w * p2s[w].w;
    dp = wave_allsum(dp);

    if (l == 0) {
        diag[g] = dp;                                   // p1 . p2 (exact fp32)
        const float c2v = fmaxf(s1 + s2 - 2.0f * dp, 0.0f);
        centerArr[g] = sqrtf(c2v);                      // ||p1 - p2||
    }
}

// ---------------- Kernel B: sim = p1 @ p2^T, m97-style LDS-staged MFMA -------
// 128x128 block tile, BK=64, 4 waves in 2x2, 64x64 per wave.
// LDS linear [128][64] bf16 per operand; T2 swizzle applied by pre-swizzling
// the per-lane global source (global_load_lds writes linearly) and XOR-ing
// the ds_read column:  physcol = col ^ ((row&7)<<4)   (byte units, 16B quanta).
__global__ __launch_bounds__(256, 4) void sim_lds_kernel(
    const unsigned short* __restrict__ p1b, const unsigned short* __restrict__ p2b,
    float* __restrict__ rowsum, float* __restrict__ colsum)
{
    __shared__ __align__(16) unsigned char lds[32768];   // A: [0,16K)  B: [16K,32K)
    const int tid  = threadIdx.x;
    const int lane = tid & 63;
    const int wid  = tid >> 6;
    const int wm = wid >> 1, wn = wid & 1;
    const int row0 = blockIdx.y * 128;
    const int col0 = blockIdx.x * 128;
    const int lr  = lane & 15;     // M/N index within 16x16 fragment
    const int lkb = lane >> 4;     // k-subgroup 0..3

    // staging geometry: each 1KB chunk = 8 rows x 128B; lane covers
    // physical (row = chunk*8 + lane/8, colbyte = (lane&7)*16).
    // Inverse-swizzled source col: 16*((lane&7) ^ (lane/8)).
    const int srow = lane >> 3;
    const int scol = ((lane & 7) ^ srow) << 4;
    const int ch0  = wid * 4;      // 4 chunks per wave per operand

    f32x4 acc[4][4];
    #pragma unroll
    for (int mi = 0; mi < 4; ++mi)
        #pragma unroll
        for (int ni = 0; ni < 4; ++ni) {
            acc[mi][ni][0] = 0.f; acc[mi][ni][1] = 0.f;
            acc[mi][ni][2] = 0.f; acc[mi][ni][3] = 0.f;
        }

    const char* A = (const char*)p1b;   // row stride 2048 B
    const char* B = (const char*)p2b;

    for (int kt = 0; kt < 16; ++kt) {
        const size_t kbyte = (size_t)kt * 128;
        #pragma unroll
        for (int c = 0; c < 4; ++c) {
            const int chunk = ch0 + c;
            const int r = chunk * 8 + srow;
            gload16(A + (size_t)(row0 + r) * 2048 + kbyte + scol, lds + chunk * 1024);
            gload16(B + (size_t)(col0 + r) * 2048 + kbyte + scol, lds + 16384 + chunk * 1024);
        }
        __syncthreads();   // drains vmcnt -> staged data visible

        #pragma unroll
        for (int ks = 0; ks < 2; ++ks) {
            bf16x8 af[4], bg[4];
            const int cbase = (ks * 64 + lkb * 16) ^ ((lr & 7) << 4);
            #pragma unroll
            for (int i = 0; i < 4; ++i) {
                const int ra = wm * 64 + i * 16 + lr;
                const int rb = wn * 64 + i * 16 + lr;
                af[i] = *reinterpret_cast<const bf16x8*>(lds + ra * 128 + cbase);
                bg[i] = *reinterpret_cast<const bf16x8*>(lds + 16384 + rb * 128 + cbase);
            }
            #pragma unroll
            for (int mi = 0; mi < 4; ++mi)
                #pragma unroll
                for (int ni = 0; ni < 4; ++ni)
                    acc[mi][ni] = __builtin_amdgcn_mfma_f32_16x16x32_bf16(
                        af[mi], bg[ni], acc[mi][ni], 0, 0, 0);
        }
        __syncthreads();   // reads done before next stage overwrites
    }

    // exp() and row/col partial sums.
    // D layout: row = mi*16 + lkb*4 + r (r = reg), col = ni*16 + lr.
    float rs[4][4];
    float cs[4] = {0.f, 0.f, 0.f, 0.f};
    #pragma unroll
    for (int mi = 0; mi < 4; ++mi)
        #pragma unroll
        for (int r = 0; r < 4; ++r) rs[mi][r] = 0.f;

    #pragma unroll
    for (int mi = 0; mi < 4; ++mi)
        #pragma unroll
        for (int ni = 0; ni < 4; ++ni)
            #pragma unroll
            for (int r = 0; r < 4; ++r) {
                float e = __expf(acc[mi][ni][r]);
                rs[mi][r] += e;
                cs[ni] += e;
            }

    const int wrow0 = row0 + wm * 64;
    const int wcol0 = col0 + wn * 64;
    #pragma unroll
    for (int mi = 0; mi < 4; ++mi)
        #pragma unroll
        for (int r = 0; r < 4; ++r) {
            float v = rs[mi][r];
            v += __shfl_xor(v, 1, 64);
            v += __shfl_xor(v, 2, 64);
            v += __shfl_xor(v, 4, 64);
            v += __shfl_xor(v, 8, 64);
            if (lr == 0) atomicAdd(&rowsum[wrow0 + mi * 16 + lkb * 4 + r], v);
        }
    #pragma unroll
    for (int ni = 0; ni < 4; ++ni) {
        float v = cs[ni];
        v += __shfl_xor(v, 16, 64);
        v += __shfl_xor(v, 32, 64);
        if (lkb == 0) atomicAdd(&colsum[wcol0 + ni * 16 + lr], v);
    }
}

// ---------------- fallback sim (no ws): read fp32 p1/p2 from out -------------
__device__ __forceinline__ bf16x8 frag_from_f32(const float* p) {
    bf16x8 r;
    #pragma unroll
    for (int i = 0; i < 8; ++i) {
        unsigned int b = __float_as_uint(p[i]);
        b += 0x7fffu + ((b >> 16) & 1u);   // RNE to bf16
        r[i] = (short)(b >> 16);
    }
    return r;
}

__global__ __launch_bounds__(256) void sim_fallback_kernel(
    const float* __restrict__ p1f, const float* __restrict__ p2f,
    float* __restrict__ rowsum, float* __restrict__ colsum)
{
    const int lane = threadIdx.x & 63;
    const int wid  = threadIdx.x >> 6;
    const int wm = wid >> 1, wn = wid & 1;
    const int row0 = blockIdx.y * 128 + wm * 64;
    const int col0 = blockIdx.x * 128 + wn * 64;
    const int lr  = lane & 15;
    const int lkb = lane >> 4;
    const int lk  = lkb * 8;

    f32x4 acc[4][4];
    #pragma unroll
    for (int mi = 0; mi < 4; ++mi)
        #pragma unroll
        for (int ni = 0; ni < 4; ++ni) {
            acc[mi][ni][0] = 0.f; acc[mi][ni][1] = 0.f;
            acc[mi][ni][2] = 0.f; acc[mi][ni][3] = 0.f;
        }

    const size_t abase = (size_t)(row0 + lr) * CDIM + lk;
    const size_t bbase = (size_t)(col0 + lr) * CDIM + lk;

    for (int k = 0; k < CDIM; k += 32) {
        bf16x8 af[4], bfr[4];
        #pragma unroll
        for (int i = 0; i < 4; ++i) {
            af[i]  = frag_from_f32(p1f + abase + (size_t)i * 16 * CDIM + k);
            bfr[i] = frag_from_f32(p2f + bbase + (size_t)i * 16 * CDIM + k);
        }
        #pragma unroll
        for (int mi = 0; mi < 4; ++mi)
            #pragma unroll
            for (int ni = 0; ni < 4; ++ni)
                acc[mi][ni] = __builtin_amdgcn_mfma_f32_16x16x32_bf16(
                    af[mi], bfr[ni], acc[mi][ni], 0, 0, 0);
    }

    float rs[4][4];
    float cs[4] = {0.f, 0.f, 0.f, 0.f};
    #pragma unroll
    for (int mi = 0; mi < 4; ++mi)
        #pragma unroll
        for (int r = 0; r < 4; ++r) rs[mi][r] = 0.f;

    #pragma unroll
    for (int mi = 0; mi < 4; ++mi)
        #pragma unroll
        for (int ni = 0; ni < 4; ++ni)
            #pragma unroll
            for (int r = 0; r < 4; ++r) {
                float e = __expf(acc[mi][ni][r]);
                rs[mi][r] += e;
                cs[ni] += e;
            }

    #pragma unroll
    for (int mi = 0; mi < 4; ++mi)
        #pragma unroll
        for (int r = 0; r < 4; ++r) {
            float v = rs[mi][r];
            v += __shfl_xor(v, 1, 64);
            v += __shfl_xor(v, 2, 64);
            v += __shfl_xor(v, 4, 64);
            v += __shfl_xor(v, 8, 64);
            if (lr == 0) atomicAdd(&rowsum[row0 + mi * 16 + lkb * 4 + r], v);
        }
    #pragma unroll
    for (int ni = 0; ni < 4; ++ni) {
        float v = cs[ni];
        v += __shfl_xor(v, 16, 64);
        v += __shfl_xor(v, 32, 64);
        if (lkb == 0) atomicAdd(&colsum[col0 + ni * 16 + lr], v);
    }
}

// ---------------- Kernel C: final scalar loss ---------------------------------
__global__ __launch_bounds__(256) void loss_kernel(
    const float* __restrict__ rowsum, const float* __restrict__ colsum,
    const float* __restrict__ diag, const float* __restrict__ centerArr,
    float* __restrict__ out)
{
    float part = 0.f;
    for (int i = threadIdx.x; i < BGRP; i += 256)
        part += logf(rowsum[i]) + logf(colsum[i]) - 2.0f * diag[i] + centerArr[i];
    #pragma unroll
    for (int off = 32; off > 0; off >>= 1) part += __shfl_down(part, off, 64);
    __shared__ float l4[4];
    if ((threadIdx.x & 63) == 0) l4[threadIdx.x >> 6] = part;
    __syncthreads();
    if (threadIdx.x == 0)
        out[0] = (l4[0] + l4[1] + l4[2] + l4[3]) * (1.0f / (float)BGRP);
}

// ---------------- launch ------------------------------------------------------
extern "C" void kernel_launch(void* const* d_in, const int* in_sizes, int n_in,
                              void* d_out, int out_size, void* d_ws, size_t ws_size,
                              hipStream_t stream)
{
    const float* x1 = (const float*)d_in[0];
    const float* x2 = (const float*)d_in[1];
    float* out = (float*)d_out;

    float* rowsum    = (float*)d_ws;            // 4096
    float* colsum    = rowsum + BGRP;           // 4096
    float* diag      = colsum + BGRP;           // 4096
    float* centerArr = diag + BGRP;             // 4096
    const size_t head_floats = 4 * (size_t)BGRP;       // 64 KB, 16B aligned
    unsigned short* p1b = (unsigned short*)((char*)d_ws + head_floats * sizeof(float));
    unsigned short* p2b = p1b + (size_t)BGRP * CDIM;
    const size_t need = head_floats * sizeof(float) + (size_t)2 * BGRP * CDIM * sizeof(unsigned short);
    const bool use_ws = (ws_size >= need);

    // only rowsum/colsum need zeroing (diag/centerArr fully overwritten)
    hipMemsetAsync(d_ws, 0, 2 * (size_t)BGRP * sizeof(float), stream);

    pool_kernel<<<BGRP / 4, 256, 0, stream>>>(x1, x2, out,
                                              use_ws ? p1b : nullptr,
                                              use_ws ? p2b : nullptr,
                                              diag, centerArr);

    dim3 gridB(BGRP / 128, BGRP / 128);
    if (use_ws) {
        sim_lds_kernel<<<gridB, 256, 0, stream>>>(p1b, p2b, rowsum, colsum);
    } else {
        sim_fallback_kernel<<<gridB, 256, 0, stream>>>(out + 1, out + 1 + (size_t)BGRP * CDIM,
                                                       rowsum, colsum);
    }

    loss_kernel<<<1, 256, 0, stream>>>(rowsum, colsum, diag, centerArr, out);
}

// Round 4
// 86.235 us; speedup vs baseline: 2.4835x; 1.0120x over previous
//
#include <hip/hip_runtime.h>
#include <hip/hip_bf16.h>

// Shapes fixed by the reference: N=16384 rows, C=1024, b=4096 groups of 4.
#define BGRP 4096
#define CDIM 1024

typedef __attribute__((ext_vector_type(8))) short bf16x8;
typedef __attribute__((ext_vector_type(4))) float f32x4;
typedef __attribute__((ext_vector_type(4))) unsigned short u16x4;

__device__ __forceinline__ unsigned short f2bf(float x) {
    __hip_bfloat16 h = __float2bfloat16(x);
    unsigned short u;
    __builtin_memcpy(&u, &h, 2);
    return u;
}

__device__ __forceinline__ void gload16(const void* g, void* l) {
    __builtin_amdgcn_global_load_lds(
        (const __attribute__((address_space(1))) unsigned int*)g,
        (__attribute__((address_space(3))) unsigned int*)l, 16, 0, 0);
}

// d: 10 packed upper-tri dots (raw rows, order (0,0),(0,1)..(3,3))
// coef[i] = softmax_i(sum_j G_ij) * inv_norm_i   where G = normalized Gram
__device__ __forceinline__ void group_coefs(const float* d, float* coef) {
    float D[4][4];
    int c = 0;
    #pragma unroll
    for (int i = 0; i < 4; ++i)
        #pragma unroll
        for (int j = i; j < 4; ++j) { D[i][j] = d[c]; D[j][i] = d[c]; ++c; }
    float inv[4];
    #pragma unroll
    for (int i = 0; i < 4; ++i) inv[i] = 1.0f / fmaxf(sqrtf(D[i][i]), 1e-12f);
    float s[4];
    #pragma unroll
    for (int i = 0; i < 4; ++i) {
        float si = 0.f;
        #pragma unroll
        for (int j = 0; j < 4; ++j) si += D[i][j] * inv[i] * inv[j];
        s[i] = si;
    }
    float m = fmaxf(fmaxf(s[0], s[1]), fmaxf(s[2], s[3]));
    float e[4], se = 0.f;
    #pragma unroll
    for (int i = 0; i < 4; ++i) { e[i] = expf(s[i] - m); se += e[i]; }
    float rse = 1.0f / se;
    #pragma unroll
    for (int i = 0; i < 4; ++i) coef[i] = e[i] * rse * inv[i];
}

__device__ __forceinline__ float wave_allsum(float t) {
    t += __shfl_xor(t, 1, 64);
    t += __shfl_xor(t, 2, 64);
    t += __shfl_xor(t, 4, 64);
    t += __shfl_xor(t, 8, 64);
    t += __shfl_xor(t, 16, 64);
    t += __shfl_xor(t, 32, 64);
    return t;
}

// ---------------- Kernel A: group pooling, ONE WAVE per (group, input) -------
// Block = 4 waves = 2 groups x {x1-wave, x2-wave}. Wave-synchronous compute;
// one barrier for the p1/p2 pairing (diag & center) via an LDS exchange.
__global__ __launch_bounds__(256, 4) void pool_kernel(
    const float* __restrict__ x1, const float* __restrict__ x2,
    float* __restrict__ out,
    unsigned short* __restrict__ p1b, unsigned short* __restrict__ p2b,
    float* __restrict__ diag, float* __restrict__ centerArr)
{
    __shared__ float plds[2][CDIM];   // pooled p1 of the block's two groups
    const int l    = threadIdx.x & 63;
    const int wv   = threadIdx.x >> 6;      // 0..3
    const int gi   = wv >> 1;               // group slot in block: 0,1
    const int isx2 = wv & 1;                // 0 -> x1, 1 -> x2
    const int g    = blockIdx.x * 2 + gi;

    const float* __restrict__ x = isx2 ? x2 : x1;

    // ---- load: 16 float4 per lane (4 rows x 4 chunks), coalesced 1KB/instr --
    float4 a[4][4];
    #pragma unroll
    for (int i = 0; i < 4; ++i)
        #pragma unroll
        for (int w = 0; w < 4; ++w)
            a[i][w] = reinterpret_cast<const float4*>(x)[(size_t)(4 * g + i) * 256 + w * 64 + l];

    // ---- Gram (10 upper-tri dots) + wave butterfly reduce -------------------
    float dd[10];
    {
        int c = 0;
        #pragma unroll
        for (int i = 0; i < 4; ++i)
            #pragma unroll
            for (int j = i; j < 4; ++j) {
                float s0 = 0.f;
                #pragma unroll
                for (int w = 0; w < 4; ++w)
                    s0 += a[i][w].x * a[j][w].x + a[i][w].y * a[j][w].y
                        + a[i][w].z * a[j][w].z + a[i][w].w * a[j][w].w;
                dd[c++] = s0;
            }
    }
    #pragma unroll
    for (int v = 0; v < 10; ++v) dd[v] = wave_allsum(dd[v]);

    float coef[4];
    group_coefs(dd, coef);

    // |q|^2 closed-form from Gram: n = c^T D c  (no extra reduction)
    float D[4][4];
    {
        int c = 0;
        #pragma unroll
        for (int i = 0; i < 4; ++i)
            #pragma unroll
            for (int j = i; j < 4; ++j) { D[i][j] = dd[c]; D[j][i] = dd[c]; ++c; }
    }
    float n = 0.f;
    #pragma unroll
    for (int i = 0; i < 4; ++i) {
        float ti = 0.f;
        #pragma unroll
        for (int j = 0; j < 4; ++j) ti += D[i][j] * coef[j];
        n += coef[i] * ti;
    }
    const float inv = 1.0f / fmaxf(sqrtf(n), 1e-12f);

    // ---- pooled + normalized vector; stores + LDS deposit -------------------
    float* pout = out + 1 + (size_t)(g + (isx2 ? BGRP : 0)) * CDIM;
    unsigned short* pb = isx2 ? (p2b ? p2b + (size_t)g * CDIM : nullptr)
                              : (p1b ? p1b + (size_t)g * CDIM : nullptr);

    float4 q[4];
    #pragma unroll
    for (int w = 0; w < 4; ++w) {
        float4 qq;
        qq.x = coef[0]*a[0][w].x + coef[1]*a[1][w].x + coef[2]*a[2][w].x + coef[3]*a[3][w].x;
        qq.y = coef[0]*a[0][w].y + coef[1]*a[1][w].y + coef[2]*a[2][w].y + coef[3]*a[3][w].y;
        qq.z = coef[0]*a[0][w].z + coef[1]*a[1][w].z + coef[2]*a[2][w].z + coef[3]*a[3][w].z;
        qq.w = coef[0]*a[0][w].w + coef[1]*a[1][w].w + coef[2]*a[2][w].w + coef[3]*a[3][w].w;
        qq.x *= inv; qq.y *= inv; qq.z *= inv; qq.w *= inv;
        q[w] = qq;
    }

    // x1-waves deposit p1 into LDS first (shortens the barrier wait)
    if (!isx2) {
        #pragma unroll
        for (int w = 0; w < 4; ++w)
            *reinterpret_cast<float4*>(&plds[gi][w * 256 + l * 4]) = q[w];
    }

    #pragma unroll
    for (int w = 0; w < 4; ++w) {
        const int e = w * 256 + l * 4;
        pout[e + 0] = q[w].x; pout[e + 1] = q[w].y;
        pout[e + 2] = q[w].z; pout[e + 3] = q[w].w;
        if (pb != nullptr) {
            u16x4 wb;
            wb[0] = f2bf(q[w].x); wb[1] = f2bf(q[w].y);
            wb[2] = f2bf(q[w].z); wb[3] = f2bf(q[w].w);
            *reinterpret_cast<u16x4*>(pb + e) = wb;
        }
    }

    __syncthreads();

    // x2-waves: dp = p1 . p2 ; diag & center
    if (isx2) {
        float dp = 0.f;
        #pragma unroll
        for (int w = 0; w < 4; ++w) {
            float4 p1v = *reinterpret_cast<const float4*>(&plds[gi][w * 256 + l * 4]);
            dp += p1v.x * q[w].x + p1v.y * q[w].y + p1v.z * q[w].z + p1v.w * q[w].w;
        }
        dp = wave_allsum(dp);
        if (l == 0) {
            diag[g] = dp;                               // p1 . p2 (fp32)
            centerArr[g] = sqrtf(fmaxf(2.0f - 2.0f * dp, 0.0f));   // ||p1-p2||, |p|=1
        }
    }
}

// ---------------- Kernel B: sim = p1 @ p2^T, m97-style LDS-staged MFMA -------
// 128x128 block tile, BK=64, 4 waves in 2x2, 64x64 per wave.
// LDS linear [128][64] bf16 per operand; T2 swizzle applied by pre-swizzling
// the per-lane global source (global_load_lds writes linearly) and XOR-ing
// the ds_read column:  physcol = col ^ ((row&7)<<4)   (byte units, 16B quanta).
__global__ __launch_bounds__(256, 4) void sim_lds_kernel(
    const unsigned short* __restrict__ p1b, const unsigned short* __restrict__ p2b,
    float* __restrict__ rowsum, float* __restrict__ colsum)
{
    __shared__ __align__(16) unsigned char lds[32768];   // A: [0,16K)  B: [16K,32K)
    const int tid  = threadIdx.x;
    const int lane = tid & 63;
    const int wid  = tid >> 6;
    const int wm = wid >> 1, wn = wid & 1;
    const int row0 = blockIdx.y * 128;
    const int col0 = blockIdx.x * 128;
    const int lr  = lane & 15;     // M/N index within 16x16 fragment
    const int lkb = lane >> 4;     // k-subgroup 0..3

    // staging geometry: each 1KB chunk = 8 rows x 128B; lane covers
    // physical (row = chunk*8 + lane/8, colbyte = (lane&7)*16).
    // Inverse-swizzled source col: 16*((lane&7) ^ (lane/8)).
    const int srow = lane >> 3;
    const int scol = ((lane & 7) ^ srow) << 4;
    const int ch0  = wid * 4;      // 4 chunks per wave per operand

    f32x4 acc[4][4];
    #pragma unroll
    for (int mi = 0; mi < 4; ++mi)
        #pragma unroll
        for (int ni = 0; ni < 4; ++ni) {
            acc[mi][ni][0] = 0.f; acc[mi][ni][1] = 0.f;
            acc[mi][ni][2] = 0.f; acc[mi][ni][3] = 0.f;
        }

    const char* A = (const char*)p1b;   // row stride 2048 B
    const char* B = (const char*)p2b;

    for (int kt = 0; kt < 16; ++kt) {
        const size_t kbyte = (size_t)kt * 128;
        #pragma unroll
        for (int c = 0; c < 4; ++c) {
            const int chunk = ch0 + c;
            const int r = chunk * 8 + srow;
            gload16(A + (size_t)(row0 + r) * 2048 + kbyte + scol, lds + chunk * 1024);
            gload16(B + (size_t)(col0 + r) * 2048 + kbyte + scol, lds + 16384 + chunk * 1024);
        }
        __syncthreads();   // drains vmcnt -> staged data visible

        #pragma unroll
        for (int ks = 0; ks < 2; ++ks) {
            bf16x8 af[4], bg[4];
            const int cbase = (ks * 64 + lkb * 16) ^ ((lr & 7) << 4);
            #pragma unroll
            for (int i = 0; i < 4; ++i) {
                const int ra = wm * 64 + i * 16 + lr;
                const int rb = wn * 64 + i * 16 + lr;
                af[i] = *reinterpret_cast<const bf16x8*>(lds + ra * 128 + cbase);
                bg[i] = *reinterpret_cast<const bf16x8*>(lds + 16384 + rb * 128 + cbase);
            }
            #pragma unroll
            for (int mi = 0; mi < 4; ++mi)
                #pragma unroll
                for (int ni = 0; ni < 4; ++ni)
                    acc[mi][ni] = __builtin_amdgcn_mfma_f32_16x16x32_bf16(
                        af[mi], bg[ni], acc[mi][ni], 0, 0, 0);
        }
        __syncthreads();   // reads done before next stage overwrites
    }

    // exp() and row/col partial sums.
    // D layout: row = mi*16 + lkb*4 + r (r = reg), col = ni*16 + lr.
    float rs[4][4];
    float cs[4] = {0.f, 0.f, 0.f, 0.f};
    #pragma unroll
    for (int mi = 0; mi < 4; ++mi)
        #pragma unroll
        for (int r = 0; r < 4; ++r) rs[mi][r] = 0.f;

    #pragma unroll
    for (int mi = 0; mi < 4; ++mi)
        #pragma unroll
        for (int ni = 0; ni < 4; ++ni)
            #pragma unroll
            for (int r = 0; r < 4; ++r) {
                float e = __expf(acc[mi][ni][r]);
                rs[mi][r] += e;
                cs[ni] += e;
            }

    const int wrow0 = row0 + wm * 64;
    const int wcol0 = col0 + wn * 64;
    #pragma unroll
    for (int mi = 0; mi < 4; ++mi)
        #pragma unroll
        for (int r = 0; r < 4; ++r) {
            float v = rs[mi][r];
            v += __shfl_xor(v, 1, 64);
            v += __shfl_xor(v, 2, 64);
            v += __shfl_xor(v, 4, 64);
            v += __shfl_xor(v, 8, 64);
            if (lr == 0) atomicAdd(&rowsum[wrow0 + mi * 16 + lkb * 4 + r], v);
        }
    #pragma unroll
    for (int ni = 0; ni < 4; ++ni) {
        float v = cs[ni];
        v += __shfl_xor(v, 16, 64);
        v += __shfl_xor(v, 32, 64);
        if (lkb == 0) atomicAdd(&colsum[wcol0 + ni * 16 + lr], v);
    }
}

// ---------------- fallback sim (no ws): read fp32 p1/p2 from out -------------
__device__ __forceinline__ bf16x8 frag_from_f32(const float* p) {
    bf16x8 r;
    #pragma unroll
    for (int i = 0; i < 8; ++i) {
        unsigned int b = __float_as_uint(p[i]);
        b += 0x7fffu + ((b >> 16) & 1u);   // RNE to bf16
        r[i] = (short)(b >> 16);
    }
    return r;
}

__global__ __launch_bounds__(256) void sim_fallback_kernel(
    const float* __restrict__ p1f, const float* __restrict__ p2f,
    float* __restrict__ rowsum, float* __restrict__ colsum)
{
    const int lane = threadIdx.x & 63;
    const int wid  = threadIdx.x >> 6;
    const int wm = wid >> 1, wn = wid & 1;
    const int row0 = blockIdx.y * 128 + wm * 64;
    const int col0 = blockIdx.x * 128 + wn * 64;
    const int lr  = lane & 15;
    const int lkb = lane >> 4;
    const int lk  = lkb * 8;

    f32x4 acc[4][4];
    #pragma unroll
    for (int mi = 0; mi < 4; ++mi)
        #pragma unroll
        for (int ni = 0; ni < 4; ++ni) {
            acc[mi][ni][0] = 0.f; acc[mi][ni][1] = 0.f;
            acc[mi][ni][2] = 0.f; acc[mi][ni][3] = 0.f;
        }

    const size_t abase = (size_t)(row0 + lr) * CDIM + lk;
    const size_t bbase = (size_t)(col0 + lr) * CDIM + lk;

    for (int k = 0; k < CDIM; k += 32) {
        bf16x8 af[4], bfr[4];
        #pragma unroll
        for (int i = 0; i < 4; ++i) {
            af[i]  = frag_from_f32(p1f + abase + (size_t)i * 16 * CDIM + k);
            bfr[i] = frag_from_f32(p2f + bbase + (size_t)i * 16 * CDIM + k);
        }
        #pragma unroll
        for (int mi = 0; mi < 4; ++mi)
            #pragma unroll
            for (int ni = 0; ni < 4; ++ni)
                acc[mi][ni] = __builtin_amdgcn_mfma_f32_16x16x32_bf16(
                    af[mi], bfr[ni], acc[mi][ni], 0, 0, 0);
    }

    float rs[4][4];
    float cs[4] = {0.f, 0.f, 0.f, 0.f};
    #pragma unroll
    for (int mi = 0; mi < 4; ++mi)
        #pragma unroll
        for (int r = 0; r < 4; ++r) rs[mi][r] = 0.f;

    #pragma unroll
    for (int mi = 0; mi < 4; ++mi)
        #pragma unroll
        for (int ni = 0; ni < 4; ++ni)
            #pragma unroll
            for (int r = 0; r < 4; ++r) {
                float e = __expf(acc[mi][ni][r]);
                rs[mi][r] += e;
                cs[ni] += e;
            }

    #pragma unroll
    for (int mi = 0; mi < 4; ++mi)
        #pragma unroll
        for (int r = 0; r < 4; ++r) {
            float v = rs[mi][r];
            v += __shfl_xor(v, 1, 64);
            v += __shfl_xor(v, 2, 64);
            v += __shfl_xor(v, 4, 64);
            v += __shfl_xor(v, 8, 64);
            if (lr == 0) atomicAdd(&rowsum[row0 + mi * 16 + lkb * 4 + r], v);
        }
    #pragma unroll
    for (int ni = 0; ni < 4; ++ni) {
        float v = cs[ni];
        v += __shfl_xor(v, 16, 64);
        v += __shfl_xor(v, 32, 64);
        if (lkb == 0) atomicAdd(&colsum[col0 + ni * 16 + lr], v);
    }
}

// ---------------- Kernel C: final scalar loss ---------------------------------
__global__ __launch_bounds__(256) void loss_kernel(
    const float* __restrict__ rowsum, const float* __restrict__ colsum,
    const float* __restrict__ diag, const float* __restrict__ centerArr,
    float* __restrict__ out)
{
    float part = 0.f;
    for (int i = threadIdx.x; i < BGRP; i += 256)
        part += logf(rowsum[i]) + logf(colsum[i]) - 2.0f * diag[i] + centerArr[i];
    #pragma unroll
    for (int off = 32; off > 0; off >>= 1) part += __shfl_down(part, off, 64);
    __shared__ float l4[4];
    if ((threadIdx.x & 63) == 0) l4[threadIdx.x >> 6] = part;
    __syncthreads();
    if (threadIdx.x == 0)
        out[0] = (l4[0] + l4[1] + l4[2] + l4[3]) * (1.0f / (float)BGRP);
}

// ---------------- launch ------------------------------------------------------
extern "C" void kernel_launch(void* const* d_in, const int* in_sizes, int n_in,
                              void* d_out, int out_size, void* d_ws, size_t ws_size,
                              hipStream_t stream)
{
    const float* x1 = (const float*)d_in[0];
    const float* x2 = (const float*)d_in[1];
    float* out = (float*)d_out;

    float* rowsum    = (float*)d_ws;            // 4096
    float* colsum    = rowsum + BGRP;           // 4096
    float* diag      = colsum + BGRP;           // 4096
    float* centerArr = diag + BGRP;             // 4096
    const size_t head_floats = 4 * (size_t)BGRP;       // 64 KB, 16B aligned
    unsigned short* p1b = (unsigned short*)((char*)d_ws + head_floats * sizeof(float));
    unsigned short* p2b = p1b + (size_t)BGRP * CDIM;
    const size_t need = head_floats * sizeof(float) + (size_t)2 * BGRP * CDIM * sizeof(unsigned short);
    const bool use_ws = (ws_size >= need);

    // only rowsum/colsum need zeroing (diag/centerArr fully overwritten)
    hipMemsetAsync(d_ws, 0, 2 * (size_t)BGRP * sizeof(float), stream);

    pool_kernel<<<BGRP / 2, 256, 0, stream>>>(x1, x2, out,
                                              use_ws ? p1b : nullptr,
                                              use_ws ? p2b : nullptr,
                                              diag, centerArr);

    dim3 gridB(BGRP / 128, BGRP / 128);
    if (use_ws) {
        sim_lds_kernel<<<gridB, 256, 0, stream>>>(p1b, p2b, rowsum, colsum);
    } else {
        sim_fallback_kernel<<<gridB, 256, 0, stream>>>(out + 1, out + 1 + (size_t)BGRP * CDIM,
                                                       rowsum, colsum);
    }

    loss_kernel<<<1, 256, 0, stream>>>(rowsum, colsum, diag, centerArr, out);
}

// Round 5
// 81.017 us; speedup vs baseline: 2.6435x; 1.0644x over previous
//
#include <hip/hip_runtime.h>
#include <hip/hip_bf16.h>

// Shapes fixed by the reference: N=16384 rows, C=1024, b=4096 groups of 4.
#define BGRP 4096
#define CDIM 1024

typedef __attribute__((ext_vector_type(8))) short bf16x8;
typedef __attribute__((ext_vector_type(4))) float f32x4;
typedef __attribute__((ext_vector_type(4))) unsigned short u16x4;

__device__ __forceinline__ unsigned short f2bf(float x) {
    __hip_bfloat16 h = __float2bfloat16(x);
    unsigned short u;
    __builtin_memcpy(&u, &h, 2);
    return u;
}

__device__ __forceinline__ void gload16(const void* g, void* l) {
    __builtin_amdgcn_global_load_lds(
        (const __attribute__((address_space(1))) unsigned int*)g,
        (__attribute__((address_space(3))) unsigned int*)l, 16, 0, 0);
}

__device__ __forceinline__ float4 ld4(const float* __restrict__ x, size_t idx4) {
    return reinterpret_cast<const float4*>(x)[idx4];
}

// d: 10 packed upper-tri dots (raw rows, order (0,0),(0,1)..(3,3))
// coef[i] = softmax_i(sum_j G_ij) * inv_norm_i   where G = normalized Gram
__device__ __forceinline__ void group_coefs(const float* d, float* coef) {
    float D[4][4];
    int c = 0;
    #pragma unroll
    for (int i = 0; i < 4; ++i)
        #pragma unroll
        for (int j = i; j < 4; ++j) { D[i][j] = d[c]; D[j][i] = d[c]; ++c; }
    float inv[4];
    #pragma unroll
    for (int i = 0; i < 4; ++i) inv[i] = 1.0f / fmaxf(sqrtf(D[i][i]), 1e-12f);
    float s[4];
    #pragma unroll
    for (int i = 0; i < 4; ++i) {
        float si = 0.f;
        #pragma unroll
        for (int j = 0; j < 4; ++j) si += D[i][j] * inv[i] * inv[j];
        s[i] = si;
    }
    float m = fmaxf(fmaxf(s[0], s[1]), fmaxf(s[2], s[3]));
    float e[4], se = 0.f;
    #pragma unroll
    for (int i = 0; i < 4; ++i) { e[i] = expf(s[i] - m); se += e[i]; }
    float rse = 1.0f / se;
    #pragma unroll
    for (int i = 0; i < 4; ++i) coef[i] = e[i] * rse * inv[i];
}

__device__ __forceinline__ float wave_allsum(float t) {
    t += __shfl_xor(t, 1, 64);
    t += __shfl_xor(t, 2, 64);
    t += __shfl_xor(t, 4, 64);
    t += __shfl_xor(t, 8, 64);
    t += __shfl_xor(t, 16, 64);
    t += __shfl_xor(t, 32, 64);
    return t;
}

// ---- one (group, input) pair, software-pipelined ----------------------------
// a01 carries prefetched rows 0,1 of THIS pair on entry; on exit it holds
// prefetched rows 0,1 of the NEXT pair (if PREF). p1pk: packed-bf16 pooled
// vector, written on x1 pairs, consumed (dp) on x2 pairs.
template<bool ISX2, bool PREF>
__device__ __forceinline__ void pair_compute(
    const float* __restrict__ x, int g, int l,
    float4 a01[2][4],
    const float* __restrict__ xn, int gn,
    float* __restrict__ out, unsigned short* __restrict__ pb,
    unsigned int p1pk[8],
    float* __restrict__ diag, float* __restrict__ centerArr)
{
    float4 a[4][4];
    #pragma unroll
    for (int w = 0; w < 4; ++w) { a[0][w] = a01[0][w]; a[1][w] = a01[1][w]; }

    // issue rows 2,3 of this pair
    #pragma unroll
    for (int i = 2; i < 4; ++i)
        #pragma unroll
        for (int w = 0; w < 4; ++w)
            a[i][w] = ld4(x, (size_t)(4 * g + i) * 256 + w * 64 + l);

    // Gram: rows{0,1} dots first (data already resident), rows{2,3} after.
    float dd[10];
    {
        auto dot = [&](int i, int j) {
            float s0 = 0.f;
            #pragma unroll
            for (int w = 0; w < 4; ++w)
                s0 += a[i][w].x * a[j][w].x + a[i][w].y * a[j][w].y
                    + a[i][w].z * a[j][w].z + a[i][w].w * a[j][w].w;
            return s0;
        };
        dd[0] = dot(0, 0); dd[1] = dot(0, 1); dd[4] = dot(1, 1);
        dd[2] = dot(0, 2); dd[3] = dot(0, 3);
        dd[5] = dot(1, 2); dd[6] = dot(1, 3);
        dd[7] = dot(2, 2); dd[8] = dot(2, 3); dd[9] = dot(3, 3);
    }
    #pragma unroll
    for (int v = 0; v < 10; ++v) dd[v] = wave_allsum(dd[v]);

    float coef[4];
    group_coefs(dd, coef);

    // |q|^2 closed-form from Gram: n = c^T D c
    float D[4][4];
    {
        int c = 0;
        #pragma unroll
        for (int i = 0; i < 4; ++i)
            #pragma unroll
            for (int j = i; j < 4; ++j) { D[i][j] = dd[c]; D[j][i] = dd[c]; ++c; }
    }
    float n = 0.f;
    #pragma unroll
    for (int i = 0; i < 4; ++i) {
        float ti = 0.f;
        #pragma unroll
        for (int j = 0; j < 4; ++j) ti += D[i][j] * coef[j];
        n += coef[i] * ti;
    }
    const float inv = 1.0f / fmaxf(sqrtf(n), 1e-12f);

    // prefetch rows 0,1 of the NEXT pair (in flight across the store phase
    // and the next pair's Gram)
    if (PREF) {
        #pragma unroll
        for (int i = 0; i < 2; ++i)
            #pragma unroll
            for (int w = 0; w < 4; ++w)
                a01[i][w] = ld4(xn, (size_t)(4 * gn + i) * 256 + w * 64 + l);
    }

    float dp = 0.f;
    #pragma unroll
    for (int w = 0; w < 4; ++w) {
        float4 q;
        q.x = coef[0]*a[0][w].x + coef[1]*a[1][w].x + coef[2]*a[2][w].x + coef[3]*a[3][w].x;
        q.y = coef[0]*a[0][w].y + coef[1]*a[1][w].y + coef[2]*a[2][w].y + coef[3]*a[3][w].y;
        q.z = coef[0]*a[0][w].z + coef[1]*a[1][w].z + coef[2]*a[2][w].z + coef[3]*a[3][w].z;
        q.w = coef[0]*a[0][w].w + coef[1]*a[1][w].w + coef[2]*a[2][w].w + coef[3]*a[3][w].w;
        q.x *= inv; q.y *= inv; q.z *= inv; q.w *= inv;

        const int e = w * 256 + l * 4;
        // fp32 outputs: not re-read on GPU -> nontemporal (keep L2/L3 for x)
        __builtin_nontemporal_store(q.x, out + e + 0);
        __builtin_nontemporal_store(q.y, out + e + 1);
        __builtin_nontemporal_store(q.z, out + e + 2);
        __builtin_nontemporal_store(q.w, out + e + 3);

        unsigned short b0 = f2bf(q.x), b1 = f2bf(q.y), b2 = f2bf(q.z), b3 = f2bf(q.w);
        if (pb != nullptr) {
            u16x4 wb; wb[0] = b0; wb[1] = b1; wb[2] = b2; wb[3] = b3;
            *reinterpret_cast<u16x4*>(pb + e) = wb;
        }
        if (!ISX2) {
            p1pk[2 * w]     = (unsigned int)b0 | ((unsigned int)b1 << 16);
            p1pk[2 * w + 1] = (unsigned int)b2 | ((unsigned int)b3 << 16);
        } else {
            // dp = p1 . p2 with p1 from packed bf16 (error ~2e-3; feeds only
            // the scalar loss, threshold 0.36)
            float p1x = __uint_as_float(p1pk[2 * w] << 16);
            float p1y = __uint_as_float(p1pk[2 * w] & 0xffff0000u);
            float p1z = __uint_as_float(p1pk[2 * w + 1] << 16);
            float p1w = __uint_as_float(p1pk[2 * w + 1] & 0xffff0000u);
            dp += p1x * q.x + p1y * q.y + p1z * q.z + p1w * q.w;
        }
    }

    if (ISX2) {
        dp = wave_allsum(dp);
        if (l == 0) {
            diag[g] = dp;
            centerArr[g] = sqrtf(fmaxf(2.0f - 2.0f * dp, 0.0f));   // |p|=1
        }
    }
}

// ---------------- Kernel A: group pooling, looped + pipelined ----------------
// 512 blocks x 4 waves; each wave handles 2 groups = 4 (g,input) pairs with
// next-pair prefetch -> loads stay in flight during every compute phase.
__global__ __launch_bounds__(256, 3) void pool_kernel(
    const float* __restrict__ x1, const float* __restrict__ x2,
    float* __restrict__ out,
    unsigned short* __restrict__ p1b, unsigned short* __restrict__ p2b,
    float* __restrict__ diag, float* __restrict__ centerArr,
    float* __restrict__ rowsum, float* __restrict__ colsum)
{
    // fused zeroing of rowsum/colsum (512 blocks x 16 = 8192 = 2*BGRP)
    if (threadIdx.x < 16) {
        rowsum[blockIdx.x * 16 + threadIdx.x] = 0.f;
        colsum[blockIdx.x * 16 + threadIdx.x] = 0.f;
    }

    const int l  = threadIdx.x & 63;
    const int W  = blockIdx.x * 4 + (threadIdx.x >> 6);   // wave id, 0..2047
    const int gA = W * 2, gB = gA + 1;

    float4 a01[2][4];
    unsigned int p1pk[8];

    // prologue: prefetch rows 0,1 of pair 0 = (gA, x1)
    #pragma unroll
    for (int i = 0; i < 2; ++i)
        #pragma unroll
        for (int w = 0; w < 4; ++w)
            a01[i][w] = ld4(x1, (size_t)(4 * gA + i) * 256 + w * 64 + l);

    float* outA1 = out + 1 + (size_t)gA * CDIM;
    float* outA2 = out + 1 + (size_t)(BGRP + gA) * CDIM;
    float* outB1 = out + 1 + (size_t)gB * CDIM;
    float* outB2 = out + 1 + (size_t)(BGRP + gB) * CDIM;

    pair_compute<false, true >(x1, gA, l, a01, x2, gA, outA1,
                               p1b ? p1b + (size_t)gA * CDIM : nullptr,
                               p1pk, diag, centerArr);
    pair_compute<true,  true >(x2, gA, l, a01, x1, gB, outA2,
                               p2b ? p2b + (size_t)gA * CDIM : nullptr,
                               p1pk, diag, centerArr);
    pair_compute<false, true >(x1, gB, l, a01, x2, gB, outB1,
                               p1b ? p1b + (size_t)gB * CDIM : nullptr,
                               p1pk, diag, centerArr);
    pair_compute<true,  false>(x2, gB, l, a01, nullptr, 0, outB2,
                               p2b ? p2b + (size_t)gB * CDIM : nullptr,
                               p1pk, diag, centerArr);
}

// ---------------- Kernel B: sim = p1 @ p2^T, m97-style LDS-staged MFMA -------
// 128x128 block tile, BK=64, 4 waves in 2x2, 64x64 per wave.
// LDS linear [128][64] bf16 per operand; T2 swizzle applied by pre-swizzling
// the per-lane global source (global_load_lds writes linearly) and XOR-ing
// the ds_read column:  physcol = col ^ ((row&7)<<4)   (byte units, 16B quanta).
__global__ __launch_bounds__(256, 4) void sim_lds_kernel(
    const unsigned short* __restrict__ p1b, const unsigned short* __restrict__ p2b,
    float* __restrict__ rowsum, float* __restrict__ colsum)
{
    __shared__ __align__(16) unsigned char lds[32768];   // A: [0,16K)  B: [16K,32K)
    const int tid  = threadIdx.x;
    const int lane = tid & 63;
    const int wid  = tid >> 6;
    const int wm = wid >> 1, wn = wid & 1;
    const int row0 = blockIdx.y * 128;
    const int col0 = blockIdx.x * 128;
    const int lr  = lane & 15;     // M/N index within 16x16 fragment
    const int lkb = lane >> 4;     // k-subgroup 0..3

    // staging geometry: each 1KB chunk = 8 rows x 128B; lane covers
    // physical (row = chunk*8 + lane/8, colbyte = (lane&7)*16).
    // Inverse-swizzled source col: 16*((lane&7) ^ (lane/8)).
    const int srow = lane >> 3;
    const int scol = ((lane & 7) ^ srow) << 4;
    const int ch0  = wid * 4;      // 4 chunks per wave per operand

    f32x4 acc[4][4];
    #pragma unroll
    for (int mi = 0; mi < 4; ++mi)
        #pragma unroll
        for (int ni = 0; ni < 4; ++ni) {
            acc[mi][ni][0] = 0.f; acc[mi][ni][1] = 0.f;
            acc[mi][ni][2] = 0.f; acc[mi][ni][3] = 0.f;
        }

    const char* A = (const char*)p1b;   // row stride 2048 B
    const char* B = (const char*)p2b;

    for (int kt = 0; kt < 16; ++kt) {
        const size_t kbyte = (size_t)kt * 128;
        #pragma unroll
        for (int c = 0; c < 4; ++c) {
            const int chunk = ch0 + c;
            const int r = chunk * 8 + srow;
            gload16(A + (size_t)(row0 + r) * 2048 + kbyte + scol, lds + chunk * 1024);
            gload16(B + (size_t)(col0 + r) * 2048 + kbyte + scol, lds + 16384 + chunk * 1024);
        }
        __syncthreads();   // drains vmcnt -> staged data visible

        #pragma unroll
        for (int ks = 0; ks < 2; ++ks) {
            bf16x8 af[4], bg[4];
            const int cbase = (ks * 64 + lkb * 16) ^ ((lr & 7) << 4);
            #pragma unroll
            for (int i = 0; i < 4; ++i) {
                const int ra = wm * 64 + i * 16 + lr;
                const int rb = wn * 64 + i * 16 + lr;
                af[i] = *reinterpret_cast<const bf16x8*>(lds + ra * 128 + cbase);
                bg[i] = *reinterpret_cast<const bf16x8*>(lds + 16384 + rb * 128 + cbase);
            }
            #pragma unroll
            for (int mi = 0; mi < 4; ++mi)
                #pragma unroll
                for (int ni = 0; ni < 4; ++ni)
                    acc[mi][ni] = __builtin_amdgcn_mfma_f32_16x16x32_bf16(
                        af[mi], bg[ni], acc[mi][ni], 0, 0, 0);
        }
        __syncthreads();   // reads done before next stage overwrites
    }

    // exp() and row/col partial sums.
    // D layout: row = mi*16 + lkb*4 + r (r = reg), col = ni*16 + lr.
    float rs[4][4];
    float cs[4] = {0.f, 0.f, 0.f, 0.f};
    #pragma unroll
    for (int mi = 0; mi < 4; ++mi)
        #pragma unroll
        for (int r = 0; r < 4; ++r) rs[mi][r] = 0.f;

    #pragma unroll
    for (int mi = 0; mi < 4; ++mi)
        #pragma unroll
        for (int ni = 0; ni < 4; ++ni)
            #pragma unroll
            for (int r = 0; r < 4; ++r) {
                float e = __expf(acc[mi][ni][r]);
                rs[mi][r] += e;
                cs[ni] += e;
            }

    const int wrow0 = row0 + wm * 64;
    const int wcol0 = col0 + wn * 64;
    #pragma unroll
    for (int mi = 0; mi < 4; ++mi)
        #pragma unroll
        for (int r = 0; r < 4; ++r) {
            float v = rs[mi][r];
            v += __shfl_xor(v, 1, 64);
            v += __shfl_xor(v, 2, 64);
            v += __shfl_xor(v, 4, 64);
            v += __shfl_xor(v, 8, 64);
            if (lr == 0) atomicAdd(&rowsum[wrow0 + mi * 16 + lkb * 4 + r], v);
        }
    #pragma unroll
    for (int ni = 0; ni < 4; ++ni) {
        float v = cs[ni];
        v += __shfl_xor(v, 16, 64);
        v += __shfl_xor(v, 32, 64);
        if (lkb == 0) atomicAdd(&colsum[wcol0 + ni * 16 + lr], v);
    }
}

// ---------------- fallback sim (no ws): read fp32 p1/p2 from out -------------
__device__ __forceinline__ bf16x8 frag_from_f32(const float* p) {
    bf16x8 r;
    #pragma unroll
    for (int i = 0; i < 8; ++i) {
        unsigned int b = __float_as_uint(p[i]);
        b += 0x7fffu + ((b >> 16) & 1u);   // RNE to bf16
        r[i] = (short)(b >> 16);
    }
    return r;
}

__global__ __launch_bounds__(256) void sim_fallback_kernel(
    const float* __restrict__ p1f, const float* __restrict__ p2f,
    float* __restrict__ rowsum, float* __restrict__ colsum)
{
    const int lane = threadIdx.x & 63;
    const int wid  = threadIdx.x >> 6;
    const int wm = wid >> 1, wn = wid & 1;
    const int row0 = blockIdx.y * 128 + wm * 64;
    const int col0 = blockIdx.x * 128 + wn * 64;
    const int lr  = lane & 15;
    const int lkb = lane >> 4;
    const int lk  = lkb * 8;

    f32x4 acc[4][4];
    #pragma unroll
    for (int mi = 0; mi < 4; ++mi)
        #pragma unroll
        for (int ni = 0; ni < 4; ++ni) {
            acc[mi][ni][0] = 0.f; acc[mi][ni][1] = 0.f;
            acc[mi][ni][2] = 0.f; acc[mi][ni][3] = 0.f;
        }

    const size_t abase = (size_t)(row0 + lr) * CDIM + lk;
    const size_t bbase = (size_t)(col0 + lr) * CDIM + lk;

    for (int k = 0; k < CDIM; k += 32) {
        bf16x8 af[4], bfr[4];
        #pragma unroll
        for (int i = 0; i < 4; ++i) {
            af[i]  = frag_from_f32(p1f + abase + (size_t)i * 16 * CDIM + k);
            bfr[i] = frag_from_f32(p2f + bbase + (size_t)i * 16 * CDIM + k);
        }
        #pragma unroll
        for (int mi = 0; mi < 4; ++mi)
            #pragma unroll
            for (int ni = 0; ni < 4; ++ni)
                acc[mi][ni] = __builtin_amdgcn_mfma_f32_16x16x32_bf16(
                    af[mi], bfr[ni], acc[mi][ni], 0, 0, 0);
    }

    float rs[4][4];
    float cs[4] = {0.f, 0.f, 0.f, 0.f};
    #pragma unroll
    for (int mi = 0; mi < 4; ++mi)
        #pragma unroll
        for (int r = 0; r < 4; ++r) rs[mi][r] = 0.f;

    #pragma unroll
    for (int mi = 0; mi < 4; ++mi)
        #pragma unroll
        for (int ni = 0; ni < 4; ++ni)
            #pragma unroll
            for (int r = 0; r < 4; ++r) {
                float e = __expf(acc[mi][ni][r]);
                rs[mi][r] += e;
                cs[ni] += e;
            }

    #pragma unroll
    for (int mi = 0; mi < 4; ++mi)
        #pragma unroll
        for (int r = 0; r < 4; ++r) {
            float v = rs[mi][r];
            v += __shfl_xor(v, 1, 64);
            v += __shfl_xor(v, 2, 64);
            v += __shfl_xor(v, 4, 64);
            v += __shfl_xor(v, 8, 64);
            if (lr == 0) atomicAdd(&rowsum[row0 + mi * 16 + lkb * 4 + r], v);
        }
    #pragma unroll
    for (int ni = 0; ni < 4; ++ni) {
        float v = cs[ni];
        v += __shfl_xor(v, 16, 64);
        v += __shfl_xor(v, 32, 64);
        if (lkb == 0) atomicAdd(&colsum[col0 + ni * 16 + lr], v);
    }
}

// ---------------- Kernel C: final scalar loss ---------------------------------
__global__ __launch_bounds__(256) void loss_kernel(
    const float* __restrict__ rowsum, const float* __restrict__ colsum,
    const float* __restrict__ diag, const float* __restrict__ centerArr,
    float* __restrict__ out)
{
    float part = 0.f;
    for (int i = threadIdx.x; i < BGRP; i += 256)
        part += __logf(rowsum[i]) + __logf(colsum[i]) - 2.0f * diag[i] + centerArr[i];
    #pragma unroll
    for (int off = 32; off > 0; off >>= 1) part += __shfl_down(part, off, 64);
    __shared__ float l4[4];
    if ((threadIdx.x & 63) == 0) l4[threadIdx.x >> 6] = part;
    __syncthreads();
    if (threadIdx.x == 0)
        out[0] = (l4[0] + l4[1] + l4[2] + l4[3]) * (1.0f / (float)BGRP);
}

// ---------------- launch ------------------------------------------------------
extern "C" void kernel_launch(void* const* d_in, const int* in_sizes, int n_in,
                              void* d_out, int out_size, void* d_ws, size_t ws_size,
                              hipStream_t stream)
{
    const float* x1 = (const float*)d_in[0];
    const float* x2 = (const float*)d_in[1];
    float* out = (float*)d_out;

    float* rowsum    = (float*)d_ws;            // 4096
    float* colsum    = rowsum + BGRP;           // 4096
    float* diag      = colsum + BGRP;           // 4096
    float* centerArr = diag + BGRP;             // 4096
    const size_t head_floats = 4 * (size_t)BGRP;       // 64 KB, 16B aligned
    unsigned short* p1b = (unsigned short*)((char*)d_ws + head_floats * sizeof(float));
    unsigned short* p2b = p1b + (size_t)BGRP * CDIM;
    const size_t need = head_floats * sizeof(float) + (size_t)2 * BGRP * CDIM * sizeof(unsigned short);
    const bool use_ws = (ws_size >= need);

    pool_kernel<<<BGRP / 8, 256, 0, stream>>>(x1, x2, out,
                                              use_ws ? p1b : nullptr,
                                              use_ws ? p2b : nullptr,
                                              diag, centerArr, rowsum, colsum);

    dim3 gridB(BGRP / 128, BGRP / 128);
    if (use_ws) {
        sim_lds_kernel<<<gridB, 256, 0, stream>>>(p1b, p2b, rowsum, colsum);
    } else {
        sim_fallback_kernel<<<gridB, 256, 0, stream>>>(out + 1, out + 1 + (size_t)BGRP * CDIM,
                                                       rowsum, colsum);
    }

    loss_kernel<<<1, 256, 0, stream>>>(rowsum, colsum, diag, centerArr, out);
}